// Round 1
// baseline (892.678 us; speedup 1.0000x reference)
//
#include <hip/hip_runtime.h>
#include <math.h>

// Fused ConvTranspose3d(32->64,k5,s2,p2) + sum(C_out) + bias + MaxPool(2) + MaxPool(3)
// x: (16,32,48,48,48) f32, weight: (32,64,5,5,5) f32, bias: (64,) f32
// out: (16,1,15,15,15) f32
//
// Derivation: y[n,od,oh,ow] = sum_{c,kd,kh,kw} x[n,c,id,ih,iw]*cw[c,kd,kh,kw], od=2*id-2+kd
//   cw = weight.sum(axis=1), cb = bias.sum()
// final out[j] = max over conv window [6j, 6j+5]^3 of y, + cb.
// Input patch per final output: id in [3j-1, 3j+3] per dim (5 wide), li = (r+4-k)/2.

#define TW 17  // w-tile width: 5 final outputs -> w positions 3*jw0-1 .. 3*jw0+15

// ---------------- Kernel 1: fold weights ----------------
__global__ void fold_kernel(const float* __restrict__ w,
                            const float* __restrict__ bias,
                            float* __restrict__ ws) {
    int gid = blockIdx.x * blockDim.x + threadIdx.x;
    if (gid < 4000) {
        int c = gid / 125, k = gid % 125;
        const float* p = w + (size_t)c * 64 * 125 + k;
        float s = 0.f;
        #pragma unroll 8
        for (int o = 0; o < 64; ++o) s += p[o * 125];
        ws[gid] = s;
    } else if (gid == 4000) {
        float s = 0.f;
        for (int o = 0; o < 64; ++o) s += bias[o];
        ws[4000] = s;
    }
}

// ---------------- Kernel 2: fused conv + maxpool ----------------
// Block = 128 threads = 5 final outputs (fo) x 6 window-d rows (rd) x 4 channel groups (cg).
// Each active thread computes the 6x6 (h,w) accumulator slab for its (fo, rd) over 8 channels
// (4 per chunk x 2 chunks), with 25+25 register-cached operands per (c, d-tap) -> 225 FMAs.
__global__ __launch_bounds__(128)
void fused_kernel(const float* __restrict__ x,
                  const float* __restrict__ ws,
                  float* __restrict__ out) {
    __shared__ __align__(16) float xt[16 * 5 * 5 * TW]; // 6800 f = 27.2 KB (16-ch chunk)
    __shared__ __align__(16) float cwS[4000];           // 16 KB
    __shared__ float red[5 * 6];

    const int tid = threadIdx.x;
    int bid = blockIdx.x;
    const int bw = bid % 3;  bid /= 3;
    const int jh = bid % 15; bid /= 15;
    const int jd = bid % 15; const int n = bid / 15;
    const int d0 = 3 * jd - 1, h0 = 3 * jh - 1, w0 = 15 * bw - 1;

    // stage folded weights (coalesced float4)
    for (int e = tid; e < 1000; e += 128)
        ((float4*)cwS)[e] = ((const float4*)ws)[e];

    const int fo = tid / 24;        // 0..4 (5 = invalid, idle lanes 120..127)
    const int r  = tid % 24;
    const int rd = r >> 2;          // 0..5
    const int cg = r & 3;           // 0..3
    const bool active = tid < 120;

    // d-dim taps for this rd: (li = lid0 - a, k = kd0 + 2a), a in [0, ntd)
    const int ntd  = (rd & 1) ? 2 : 3;
    const int kd0  = rd & 1;
    const int lid0 = (rd + 4 - kd0) >> 1;

    // h/w-dim tap tables (compile-time after unroll)
    constexpr int NTc[6]    = {3, 2, 3, 2, 3, 2};
    constexpr int LIc[6][3] = {{2,1,0},{2,1,0},{3,2,1},{3,2,0},{4,3,2},{4,3,0}};
    constexpr int KKc[6][3] = {{0,2,4},{1,3,0},{0,2,4},{1,3,0},{0,2,4},{1,3,0}};

    float acc[36];
    #pragma unroll
    for (int i = 0; i < 36; ++i) acc[i] = 0.f;

    for (int chunk = 0; chunk < 2; ++chunk) {
        __syncthreads(); // protect xt against prior chunk's readers
        // stage 16 channels: xt[c][dz][dy][dx]
        for (int e = tid; e < 6800; e += 128) {
            int dx = e % TW; int t = e / TW;
            int dy = t % 5;  t /= 5;
            int dz = t % 5;  int c = t / 5;
            int gw = w0 + dx, gh = h0 + dy, gd = d0 + dz;
            float v = 0.f;
            if (((unsigned)gw < 48u) & ((unsigned)gh < 48u) & ((unsigned)gd < 48u))
                v = x[((((size_t)n * 32 + chunk * 16 + c) * 48 + gd) * 48 + gh) * 48 + gw];
            xt[e] = v;
        }
        __syncthreads();

        if (active) {
            #pragma unroll 1
            for (int ci = 0; ci < 4; ++ci) {
                const int cl = cg * 4 + ci;           // local channel in chunk
                const int cglob = chunk * 16 + cl;    // global channel
                const float* xc = &xt[cl * (5 * 5 * TW)];
                const float* wc = &cwS[cglob * 125];
                #pragma unroll 1
                for (int a = 0; a < ntd; ++a) {
                    const int lid = lid0 - a;
                    const int kd  = kd0 + 2 * a;
                    const float* xr = xc + lid * (5 * TW) + 3 * fo;
                    const float* wr = wc + kd * 25;
                    float ib[25], wb[25];
                    #pragma unroll
                    for (int i = 0; i < 5; ++i) {
                        #pragma unroll
                        for (int j = 0; j < 5; ++j) {
                            ib[i * 5 + j] = xr[i * TW + j];
                            wb[i * 5 + j] = wr[i * 5 + j];
                        }
                    }
                    #pragma unroll
                    for (int rh = 0; rh < 6; ++rh) {
                        #pragma unroll
                        for (int b = 0; b < 3; ++b) {
                            if (b < NTc[rh]) {
                                const int lih = LIc[rh][b], kh = KKc[rh][b];
                                #pragma unroll
                                for (int rw = 0; rw < 6; ++rw) {
                                    #pragma unroll
                                    for (int e2 = 0; e2 < 3; ++e2) {
                                        if (e2 < NTc[rw]) {
                                            acc[rh * 6 + rw] =
                                                fmaf(ib[lih * 5 + LIc[rw][e2]],
                                                     wb[kh * 5 + KKc[rw][e2]],
                                                     acc[rh * 6 + rw]);
                                        }
                                    }
                                }
                            }
                        }
                    }
                }
            }
        }
    }

    // sum over cg (4 adjacent lanes), then max over the 6x6 slab
    if (active) {
        #pragma unroll
        for (int i = 0; i < 36; ++i) {
            acc[i] += __shfl_xor(acc[i], 1);
            acc[i] += __shfl_xor(acc[i], 2);
        }
        if (cg == 0) {
            float m = -INFINITY;
            #pragma unroll
            for (int i = 0; i < 36; ++i) m = fmaxf(m, acc[i]);
            red[fo * 6 + rd] = m;
        }
    }
    __syncthreads();
    if (tid < 5) {
        float m = -INFINITY;
        #pragma unroll
        for (int k = 0; k < 6; ++k) m = fmaxf(m, red[tid * 6 + k]);
        float cb = ws[4000];
        out[(((size_t)n * 15 + jd) * 15 + jh) * 15 + 5 * bw + tid] = m + cb;
    }
}

extern "C" void kernel_launch(void* const* d_in, const int* in_sizes, int n_in,
                              void* d_out, int out_size, void* d_ws, size_t ws_size,
                              hipStream_t stream) {
    const float* x = (const float*)d_in[0];
    const float* w = (const float*)d_in[1];
    const float* b = (const float*)d_in[2];
    float* out = (float*)d_out;
    float* ws  = (float*)d_ws;

    fold_kernel<<<17, 256, 0, stream>>>(w, b, ws);

    // grid: 3 jw-groups x 15 jh x 15 jd x 16 n
    fused_kernel<<<3 * 15 * 15 * 16, 128, 0, stream>>>(x, ws, out);
}